// Round 1
// baseline (48.519 us; speedup 1.0000x reference)
//
#include <hip/hip_runtime.h>

#define N1 4096
#define N2 8192
#define FDIM 256
#define HDIM 128
#define OUTD 128

// mish(x) = x * tanh(softplus(x)) = x * ((1+e^x)^2 - 1) / ((1+e^x)^2 + 1)
__device__ __forceinline__ float mishf(float x) {
    float xc = fminf(x, 30.0f);          // tanh(softplus(x)) == 1.0f beyond this
    float e = __expf(xc);
    float w = 1.0f + e;
    float w2 = w * w;
    return x * ((w2 - 1.0f) / (w2 + 1.0f));
}

// One block, 512 threads: v_m[c] = dot(w_m[c,:], a[0:128]);  v_d[c] = dot(w_d[c,:], a[256:384])
__global__ void compute_v_kernel(const float* __restrict__ w_m,
                                 const float* __restrict__ w_d,
                                 const float* __restrict__ a,
                                 float* __restrict__ v /* 512 floats: v_m | v_d */) {
    int t = threadIdx.x;
    if (t < 256) {
        const float* wr = w_m + t * OUTD;
        const float* av = a;            // a1[:128]
        float s = 0.f;
        #pragma unroll 8
        for (int o = 0; o < OUTD; ++o) s += wr[o] * av[o];
        v[t] = s;
    } else {
        int c = t - 256;
        const float* wr = w_d + c * OUTD;
        const float* av = a + 2 * OUTD; // a2[:128] = a[256:384]
        float s = 0.f;
        #pragma unroll 8
        for (int o = 0; o < OUTD; ++o) s += wr[o] * av[o];
        v[256 + c] = s;
    }
}

// One block (256 threads) per row of x (rows 0..N1-1) or y (rows N1..N1+N2-1).
// x[i] = sum_c (am0*m+am1*m1+am2*m2)[i,c] * v_m[c] + sum_h m_h[i,h]*a[128+h]
__global__ void compute_xy_kernel(const float* __restrict__ m,  const float* __restrict__ m1,
                                  const float* __restrict__ m2, const float* __restrict__ m_h,
                                  const float* __restrict__ d,  const float* __restrict__ d1,
                                  const float* __restrict__ d2, const float* __restrict__ d_h,
                                  const float* __restrict__ a_m, const float* __restrict__ a_d,
                                  const float* __restrict__ a,
                                  const float* __restrict__ v,
                                  float* __restrict__ xy /* x[0..N1) then y[N1..N1+N2) */) {
    int row = blockIdx.x;
    int tid = threadIdx.x;
    float val;
    if (row < N1) {
        float c0 = a_m[0], c1 = a_m[1], c2 = a_m[2];
        int idx = row * FDIM + tid;
        float h = c0 * m[idx] + c1 * m1[idx] + c2 * m2[idx];
        val = h * v[tid];
        if (tid < HDIM) val += m_h[row * HDIM + tid] * a[OUTD + tid];
    } else {
        int r = row - N1;
        float c0 = a_d[0], c1 = a_d[1], c2 = a_d[2];
        int idx = r * FDIM + tid;
        float h = c0 * d[idx] + c1 * d1[idx] + c2 * d2[idx];
        val = h * v[256 + tid];
        if (tid < HDIM) val += d_h[r * HDIM + tid] * a[2 * OUTD + HDIM + tid];
    }
    // wave (64-lane) shuffle reduce, then LDS combine across the 4 waves
    #pragma unroll
    for (int off = 32; off > 0; off >>= 1) val += __shfl_down(val, off, 64);
    __shared__ float sm[4];
    int wave = tid >> 6, lane = tid & 63;
    if (lane == 0) sm[wave] = val;
    __syncthreads();
    if (tid == 0) xy[row] = sm[0] + sm[1] + sm[2] + sm[3];
}

// s[i,j] = mish(x[i] + y[j]), float4-vectorized along j, grid-stride.
__global__ void mish_bcast_kernel(const float* __restrict__ x,
                                  const float* __restrict__ y,
                                  float4* __restrict__ out) {
    const unsigned JV = N2 / 4;                  // 2048 float4 per row
    const unsigned total = (unsigned)N1 * JV;    // 8,388,608
    const float4* y4 = (const float4*)y;
    for (unsigned vi = blockIdx.x * blockDim.x + threadIdx.x; vi < total;
         vi += gridDim.x * blockDim.x) {
        unsigned i  = vi >> 11;                  // / 2048
        unsigned j4 = vi & 2047;
        float xi = x[i];
        float4 yv = y4[j4];
        float4 r;
        r.x = mishf(xi + yv.x);
        r.y = mishf(xi + yv.y);
        r.z = mishf(xi + yv.z);
        r.w = mishf(xi + yv.w);
        out[vi] = r;
    }
}

extern "C" void kernel_launch(void* const* d_in, const int* in_sizes, int n_in,
                              void* d_out, int out_size, void* d_ws, size_t ws_size,
                              hipStream_t stream) {
    const float* m   = (const float*)d_in[0];
    const float* m1  = (const float*)d_in[1];
    const float* m2  = (const float*)d_in[2];
    const float* m_h = (const float*)d_in[3];
    const float* d   = (const float*)d_in[4];
    const float* d1  = (const float*)d_in[5];
    const float* d2  = (const float*)d_in[6];
    const float* d_h = (const float*)d_in[7];
    const float* w_m = (const float*)d_in[8];
    const float* w_d = (const float*)d_in[9];
    const float* a_m = (const float*)d_in[10];
    const float* a_d = (const float*)d_in[11];
    const float* a   = (const float*)d_in[12];

    float* wsf = (float*)d_ws;
    float* v  = wsf;          // 512 floats
    float* xy = wsf + 512;    // 4096 + 8192 floats

    compute_v_kernel<<<1, 512, 0, stream>>>(w_m, w_d, a, v);
    compute_xy_kernel<<<N1 + N2, 256, 0, stream>>>(m, m1, m2, m_h, d, d1, d2, d_h,
                                                   a_m, a_d, a, v, xy);
    mish_bcast_kernel<<<4096, 256, 0, stream>>>(xy, xy + N1, (float4*)d_out);
}